// Round 1
// baseline (220.070 us; speedup 1.0000x reference)
//
#include <hip/hip_runtime.h>
#include <hip/hip_bf16.h>
#include <math.h>

#define L_TOK 197
#define BTOK  128
#define DIM   768
#define CA    192
#define M_ROWS (L_TOK * BTOK)   // 25216

typedef __attribute__((ext_vector_type(8))) short  short8;
typedef __attribute__((ext_vector_type(4))) short  short4v;
typedef __attribute__((ext_vector_type(4))) float  f32x4;
typedef __attribute__((ext_vector_type(4))) float  float4v;

static __device__ __forceinline__ short f2bf(float f) {
    union { __hip_bfloat16 b; short s; } u;
    u.b = __float2bfloat16(f);
    return u.s;
}

static __device__ __forceinline__ float gelu_exact(float x) {
    return 0.5f * x * (1.0f + erff(x * 0.70710678118654752440f));
}

// ---------------------------------------------------------------------------
// Prep: w1 (768,192) fp32 -> w1T (192,768) bf16 [n][k];
//       w2 (192,768) fp32 -> w2T (768,192) bf16 [n][k]
// ---------------------------------------------------------------------------
__global__ void prep_kernel(const float* __restrict__ w1, const float* __restrict__ w2,
                            short* __restrict__ w1T, short* __restrict__ w2T) {
    int idx = blockIdx.x * 256 + threadIdx.x;
    if (idx < CA * DIM) {
        int n = idx / DIM, k = idx - n * DIM;     // w1T[n][k] = w1[k][n]
        w1T[idx] = f2bf(w1[k * CA + n]);
        int n2 = idx / CA, k2 = idx - n2 * CA;    // w2T[n2][k2] = w2[k2][n2]
        w2T[idx] = f2bf(w2[k2 * DIM + n2]);
    }
}

// ---------------------------------------------------------------------------
// GEMM1: h[m, c] = x[m, :] @ w1[:, c] + b1[c]   (M=25216, K=768, N=192)
// BM=32, BN=192, BK=32. 256 threads = 4 waves in 2(m) x 2(n).
// Wave tile: 16 rows x 96 cols = 1x6 MFMA tiles of 16x16x32 bf16.
// A converted fp32->bf16 inline during staging.
// ---------------------------------------------------------------------------
__global__ __launch_bounds__(256) void gemm1_kernel(
        const float* __restrict__ x, const short* __restrict__ w1T,
        const float* __restrict__ b1, float* __restrict__ h) {
    __shared__ __align__(16) short As[32][40];    // +8 pad: 2-way bank alias (free)
    __shared__ __align__(16) short Bs[192][40];

    const int tid  = threadIdx.x;
    const int m0   = blockIdx.x * 32;
    const int wave = tid >> 6, lane = tid & 63;
    const int wm = wave >> 1, wn = wave & 1;
    const int lm = lane & 15;
    const int lk = (lane >> 4) * 8;

    const int arow  = tid >> 3;          // 0..31, 8 threads/row -> 128B coalesced
    const int akoff = (tid & 7) * 4;
    const int brow  = tid >> 2;          // 0..63
    const int bkoff = (tid & 3) * 8;

    f32x4 acc[6] = {};

    for (int k0 = 0; k0 < DIM; k0 += 32) {
        float4v av = *(const float4v*)(x + (m0 + arow) * DIM + k0 + akoff);
        short4v a4;
        #pragma unroll
        for (int i = 0; i < 4; i++) a4[i] = f2bf(av[i]);
        short8 bv[3];
        #pragma unroll
        for (int i = 0; i < 3; i++)
            bv[i] = *(const short8*)(w1T + (i * 64 + brow) * DIM + k0 + bkoff);

        __syncthreads();
        *(short4v*)&As[arow][akoff] = a4;
        #pragma unroll
        for (int i = 0; i < 3; i++)
            *(short8*)&Bs[i * 64 + brow][bkoff] = bv[i];
        __syncthreads();

        short8 af = *(const short8*)&As[wm * 16 + lm][lk];
        #pragma unroll
        for (int j = 0; j < 6; j++) {
            short8 bf = *(const short8*)&Bs[wn * 96 + j * 16 + lm][lk];
            acc[j] = __builtin_amdgcn_mfma_f32_16x16x32_bf16(af, bf, acc[j], 0, 0, 0);
        }
    }

    // C/D layout: col = lane&15, row = (lane>>4)*4 + reg  [m89-verified]
    const int row0 = m0 + wm * 16 + (lane >> 4) * 4;
    #pragma unroll
    for (int j = 0; j < 6; j++) {
        int col = wn * 96 + j * 16 + lm;
        float bias = b1[col];
        #pragma unroll
        for (int r = 0; r < 4; r++)
            h[(row0 + r) * CA + col] = acc[j][r] + bias;
    }
}

// ---------------------------------------------------------------------------
// Middle: closed-form temporal conv + weighted sums -> result, then
// g[l,bt,c] = gelu(h[max(l,1),bt,c] + (l>=1 ? result[bt>>3, l-1, c] : 0)) (bf16)
// result[b,p,c] = cb[c] + (1/28) * sum_t coef[t,c] * h[p+1, b*8+t, c]
// coef[t,c] = (t+1)*cw0*[t<=6] + t*cw1 + (t-1)*cw2*[t>=1] - (7-t)
// Grid: (16 b) x (196 p), 192 threads (one per channel).
// ---------------------------------------------------------------------------
__global__ void mid_kernel(const float* __restrict__ h, const float* __restrict__ conv_w,
                           const float* __restrict__ conv_b, short* __restrict__ g) {
    const int c = threadIdx.x;   // 0..191
    const int b = blockIdx.x;    // 0..15
    const int p = blockIdx.y;    // 0..195
    const int l = p + 1;

    const float cw0 = conv_w[c * 3 + 0];
    const float cw1 = conv_w[c * 3 + 1];
    const float cw2 = conv_w[c * 3 + 2];
    const float cb  = conv_b[c];

    const float* hp = h + (l * BTOK + b * 8) * CA + c;
    float hv[8];
    #pragma unroll
    for (int t = 0; t < 8; t++) hv[t] = hp[t * CA];

    float s = 0.f;
    #pragma unroll
    for (int t = 0; t < 8; t++) {
        float coef = (float)t * cw1 - (float)(7 - t);
        if (t <= 6) coef += (float)(t + 1) * cw0;
        if (t >= 1) coef += (float)(t - 1) * cw2;
        s += coef * hv[t];
    }
    const float res = cb + s * (1.0f / 28.0f);

    short* gp = g + (l * BTOK + b * 8) * CA + c;
    #pragma unroll
    for (int t = 0; t < 8; t++) gp[t * CA] = f2bf(gelu_exact(hv[t] + res));

    if (p == 0) {  // out row l=0 is the trimmed row 0 = original l=1, no result added
        short* g0 = g + (b * 8) * CA + c;
        #pragma unroll
        for (int t = 0; t < 8; t++) g0[t * CA] = f2bf(gelu_exact(hv[t]));
    }
}

// ---------------------------------------------------------------------------
// GEMM2: out[m, n] = x[m, n] + g[m, :] @ w2[:, n] + b2[n]  (M=25216, K=192, N=768)
// BM=64, BN=128, BK=32. 4 waves in 2x2; wave tile 32x64 = 2x4 MFMA tiles.
// ---------------------------------------------------------------------------
__global__ __launch_bounds__(256) void gemm2_kernel(
        const short* __restrict__ g, const short* __restrict__ w2T,
        const float* __restrict__ b2, const float* __restrict__ x,
        float* __restrict__ out) {
    __shared__ __align__(16) short As[64][40];
    __shared__ __align__(16) short Bs[128][40];

    const int tid  = threadIdx.x;
    const int m0   = blockIdx.x * 64;
    const int n0   = blockIdx.y * 128;
    const int wave = tid >> 6, lane = tid & 63;
    const int wm = wave >> 1, wn = wave & 1;
    const int lm = lane & 15;
    const int lk = (lane >> 4) * 8;

    const int arow = tid >> 2;          // 0..63
    const int koff = (tid & 3) * 8;

    f32x4 acc[2][4] = {};

    for (int k0 = 0; k0 < CA; k0 += 32) {
        short8 av  = *(const short8*)(g   + (m0 + arow) * CA + k0 + koff);
        short8 bv0 = *(const short8*)(w2T + (n0 + arow) * CA + k0 + koff);
        short8 bv1 = *(const short8*)(w2T + (n0 + 64 + arow) * CA + k0 + koff);

        __syncthreads();
        *(short8*)&As[arow][koff]      = av;
        *(short8*)&Bs[arow][koff]      = bv0;
        *(short8*)&Bs[64 + arow][koff] = bv1;
        __syncthreads();

        short8 af0 = *(const short8*)&As[wm * 32 + lm][lk];
        short8 af1 = *(const short8*)&As[wm * 32 + 16 + lm][lk];
        #pragma unroll
        for (int j = 0; j < 4; j++) {
            short8 bf = *(const short8*)&Bs[wn * 64 + j * 16 + lm][lk];
            acc[0][j] = __builtin_amdgcn_mfma_f32_16x16x32_bf16(af0, bf, acc[0][j], 0, 0, 0);
            acc[1][j] = __builtin_amdgcn_mfma_f32_16x16x32_bf16(af1, bf, acc[1][j], 0, 0, 0);
        }
    }

    #pragma unroll
    for (int i = 0; i < 2; i++) {
        const int row0 = m0 + wm * 32 + i * 16 + (lane >> 4) * 4;
        #pragma unroll
        for (int j = 0; j < 4; j++) {
            int col = n0 + wn * 64 + j * 16 + lm;
            float bias = b2[col];
            #pragma unroll
            for (int r = 0; r < 4; r++) {
                int idx = (row0 + r) * DIM + col;
                out[idx] = acc[i][j][r] + x[idx] + bias;
            }
        }
    }
}

// ---------------------------------------------------------------------------
extern "C" void kernel_launch(void* const* d_in, const int* in_sizes, int n_in,
                              void* d_out, int out_size, void* d_ws, size_t ws_size,
                              hipStream_t stream) {
    (void)in_sizes; (void)n_in; (void)out_size; (void)ws_size;
    const float* x      = (const float*)d_in[0];
    const float* w1     = (const float*)d_in[1];
    const float* b1     = (const float*)d_in[2];
    const float* conv_w = (const float*)d_in[3];
    const float* conv_b = (const float*)d_in[4];
    const float* w2     = (const float*)d_in[5];
    const float* b2     = (const float*)d_in[6];
    float* out = (float*)d_out;

    char* ws = (char*)d_ws;
    float* h   = (float*)ws;                                    // 25216*192*4 = 19,365,888 B
    short* g   = (short*)(ws + 19365888);                       //  25216*192*2 = 9,682,944 B
    short* w1T = (short*)(ws + 19365888 + 9682944);             //  294,912 B
    short* w2T = (short*)(ws + 19365888 + 9682944 + 294912);    //  294,912 B

    prep_kernel<<<(CA * DIM + 255) / 256, 256, 0, stream>>>(w1, w2, w1T, w2T);
    gemm1_kernel<<<M_ROWS / 32, 256, 0, stream>>>(x, w1T, b1, h);
    mid_kernel<<<dim3(16, 196), CA, 0, stream>>>(h, conv_w, conv_b, g);
    gemm2_kernel<<<dim3(M_ROWS / 64, DIM / 128), 256, 0, stream>>>(g, w2T, b2, x, out);
}

// Round 2
// 195.787 us; speedup vs baseline: 1.1240x; 1.1240x over previous
//
#include <hip/hip_runtime.h>
#include <hip/hip_bf16.h>
#include <math.h>

#define DIM   768
#define CA    192
#define NTOK  25216   // 197*128

typedef __attribute__((ext_vector_type(8))) short short8;
typedef __attribute__((ext_vector_type(4))) float f32x4;

static __device__ __forceinline__ short f2bf(float f) {
    union { __hip_bfloat16 b; short s; } u;
    u.b = __float2bfloat16(f);
    return u.s;
}
static __device__ __forceinline__ float gelu_exact(float x) {
    return 0.5f * x * (1.0f + erff(x * 0.70710678118654752440f));
}
// async global->LDS DMA, 16B per lane; lds base must be wave-uniform.
static __device__ __forceinline__ void ld16(void* lds, const void* gsrc) {
    __builtin_amdgcn_global_load_lds((const __attribute__((address_space(1))) void*)gsrc,
                                     (__attribute__((address_space(3))) void*)lds, 16, 0, 0);
}

// ---------------------------------------------------------------------------
// Prep: w1 (768,192) -> w1T (192,768) bf16; w2 (192,768) -> w2T (768,192) bf16
// ---------------------------------------------------------------------------
__global__ void prep_kernel(const float* __restrict__ w1, const float* __restrict__ w2,
                            short* __restrict__ w1T, short* __restrict__ w2T) {
    int idx = blockIdx.x * 256 + threadIdx.x;
    if (idx < CA * DIM) {
        int n = idx / DIM, k = idx - n * DIM;
        w1T[idx] = f2bf(w1[k * CA + n]);
        int n2 = idx / CA, k2 = idx - n2 * CA;
        w2T[idx] = f2bf(w2[k2 * DIM + n2]);
    }
}

// ---------------------------------------------------------------------------
// Fused GEMM1 + temporal mix + gelu -> g (bf16).
// Block: one l (1..196), 64 rows (half of bt), 96 cols (half of CA).
// Grid 784 = 196 l * 2 halfM * 2 halfN. 4 waves 2m x 2n, wave tile 32x48.
// K-loop: BK=32, 24 iters. A: reg-prefetch + cvt + ds_write (single buffer,
// guarded by the 2 barriers). B: global_load_lds DMA, double buffer, issued
// after barrier #2 so the vmcnt drain lands one MFMA phase later.
// Bs chunk swizzle: slot = m*4 + (q ^ ((m>>1)&3)) -> b128 frag reads 2-way free.
// Epilogue: res[b,c] = cb + (1/28)*sum_t coef[t,c]*h[t]; sum via shfl_xor 16.
// ---------------------------------------------------------------------------
__global__ __launch_bounds__(256) void gemm1_fused(
        const float* __restrict__ x, const short* __restrict__ w1T,
        const float* __restrict__ b1, const float* __restrict__ conv_w,
        const float* __restrict__ conv_b, short* __restrict__ gq) {
    __shared__ __align__(16) short As[64 * 40];      // padded rows (80B) for ds_write path
    __shared__ __align__(16) short Bs[2][96 * 32];   // swizzled DMA layout

    const int tid = threadIdx.x;
    const int bx  = blockIdx.x;
    const int l   = (bx >> 2) + 1;
    const int hm  = (bx >> 1) & 1;
    const int n0  = (bx & 1) * 96;
    const int R0  = l * 128 + hm * 64;

    const int wave = tid >> 6, lane = tid & 63;
    const int wm = wave >> 1, wn = wave & 1;
    const int lm = lane & 15, lg = lane >> 4;
    const int lk = lg * 8;

    const int arow = tid >> 2;
    const int acol = (tid & 3) * 8;
    const float* xrow = x + (size_t)(R0 + arow) * DIM + acol;

    f32x4 acc[2][3] = {};

    // prolog: A(k=0) into regs, B(k=0) DMA into Bs[0]
    f32x4 av0 = *(const f32x4*)(xrow);
    f32x4 av1 = *(const f32x4*)(xrow + 4);
    if (wave < 3) {
        #pragma unroll
        for (int j = 0; j < 2; j++) {
            int s = (wave * 2 + j) * 64 + lane;
            int m = s >> 2;
            int q = (s & 3) ^ ((m >> 1) & 3);
            ld16(&Bs[0][(wave * 2 + j) * 512], w1T + (size_t)(n0 + m) * DIM + q * 8);
        }
    }

    for (int i = 0; i < 24; i++) {
        const int p = i & 1;
        short8 a8;
        #pragma unroll
        for (int e = 0; e < 4; e++) { a8[e] = f2bf(av0[e]); a8[4 + e] = f2bf(av1[e]); }
        __syncthreads();                       // #1: prev reads done; Bs[p] DMA drained
        *(short8*)&As[arow * 40 + acol] = a8;
        __syncthreads();                       // #2: As visible (nothing in vm queue here)
        if (i < 23) {
            const float* xn = xrow + (i + 1) * 32;
            av0 = *(const f32x4*)(xn);
            av1 = *(const f32x4*)(xn + 4);
            if (wave < 3) {
                const int k0n = (i + 1) * 32;
                #pragma unroll
                for (int j = 0; j < 2; j++) {
                    int s = (wave * 2 + j) * 64 + lane;
                    int m = s >> 2;
                    int q = (s & 3) ^ ((m >> 1) & 3);
                    ld16(&Bs[1 - p][(wave * 2 + j) * 512],
                         w1T + (size_t)(n0 + m) * DIM + k0n + q * 8);
                }
            }
        }
        short8 af[2], bf[3];
        af[0] = *(const short8*)&As[(wm * 32 + lm) * 40 + lk];
        af[1] = *(const short8*)&As[(wm * 32 + 16 + lm) * 40 + lk];
        #pragma unroll
        for (int j = 0; j < 3; j++) {
            int rB = wn * 48 + j * 16 + lm;
            int qs = lg ^ ((rB >> 1) & 3);
            bf[j] = *(const short8*)&Bs[p][rB * 32 + qs * 8];
        }
        #pragma unroll
        for (int i2 = 0; i2 < 2; i2++)
            #pragma unroll
            for (int j = 0; j < 3; j++)
                acc[i2][j] = __builtin_amdgcn_mfma_f32_16x16x32_bf16(af[i2], bf[j], acc[i2][j], 0, 0, 0);
    }

    // Epilogue: bias, temporal res via shfl, gelu, bf16 store. h never hits HBM.
    const int g1 = lg & 1;
    #pragma unroll
    for (int j = 0; j < 3; j++) {
        const int c = n0 + wn * 48 + j * 16 + lm;
        const float b1c = b1[c];
        const float cw0 = conv_w[c * 3 + 0];
        const float cw1 = conv_w[c * 3 + 1];
        const float cw2 = conv_w[c * 3 + 2];
        const float cb  = conv_b[c];
        #pragma unroll
        for (int i2 = 0; i2 < 2; i2++) {
            float hv[4];
            #pragma unroll
            for (int r = 0; r < 4; r++) hv[r] = acc[i2][j][r] + b1c;
            float partial = 0.f;
            #pragma unroll
            for (int r = 0; r < 4; r++) {
                const int t = g1 * 4 + r;
                const float tf = (float)t;
                float coef = tf * cw1 - (7.0f - tf);
                if (t <= 6) coef += (tf + 1.0f) * cw0;
                if (t >= 1) coef += (tf - 1.0f) * cw2;
                partial += coef * hv[r];
            }
            const float full = partial + __shfl_xor(partial, 16);
            const float res = cb + full * (1.0f / 28.0f);
            const int row = R0 + wm * 32 + i2 * 16 + lg * 4;
            #pragma unroll
            for (int r = 0; r < 4; r++)
                gq[(size_t)(row + r) * CA + c] = f2bf(gelu_exact(hv[r] + res));
            if (l == 1) {                       // out token 0 = gelu(h[l=1]) (no res)
                const int bt = row - 128;
                #pragma unroll
                for (int r = 0; r < 4; r++)
                    gq[(size_t)(bt + r) * CA + c] = f2bf(gelu_exact(hv[r]));
            }
        }
    }
}

// ---------------------------------------------------------------------------
// GEMM2: out = x + g @ w2 + b2. M=25216, K=192, N=768.
// BM=64, BN=128, BK=64 -> 3 iters; grid (394, 6). Both A and B staged via
// global_load_lds, double-buffered, one barrier per iter.
// Chunk swizzle: slot = m*8 + (q ^ (m&7)) (rows are 128B -> mandatory).
// ---------------------------------------------------------------------------
__global__ __launch_bounds__(256) void gemm2_kernel(
        const short* __restrict__ gq, const short* __restrict__ w2T,
        const float* __restrict__ b2, const float* __restrict__ x,
        float* __restrict__ out) {
    __shared__ __align__(16) short As[2][64 * 64];
    __shared__ __align__(16) short Bs[2][128 * 64];

    const int tid = threadIdx.x;
    const int m0 = blockIdx.x * 64;
    const int n0 = blockIdx.y * 128;
    const int wave = tid >> 6, lane = tid & 63;
    const int wm = wave >> 1, wn = wave & 1;
    const int lm = lane & 15, lg = lane >> 4;

    f32x4 acc[2][4] = {};

    // prolog DMA k0=0 -> buf0
    #pragma unroll
    for (int j = 0; j < 2; j++) {
        int s = (wave * 2 + j) * 64 + lane;
        int m = s >> 3, q = (s & 7) ^ (m & 7);
        ld16(&As[0][(wave * 2 + j) * 512], gq + (size_t)(m0 + m) * CA + q * 8);
    }
    #pragma unroll
    for (int j = 0; j < 4; j++) {
        int s = (wave * 4 + j) * 64 + lane;
        int m = s >> 3, q = (s & 7) ^ (m & 7);
        ld16(&Bs[0][(wave * 4 + j) * 512], w2T + (size_t)(n0 + m) * CA + q * 8);
    }

    for (int i = 0; i < 3; i++) {
        const int p = i & 1;
        __syncthreads();   // drains buf[p] DMA; guarantees buf[1-p] reads finished
        if (i < 2) {
            const int k0 = (i + 1) * 64;
            #pragma unroll
            for (int j = 0; j < 2; j++) {
                int s = (wave * 2 + j) * 64 + lane;
                int m = s >> 3, q = (s & 7) ^ (m & 7);
                ld16(&As[1 - p][(wave * 2 + j) * 512], gq + (size_t)(m0 + m) * CA + k0 + q * 8);
            }
            #pragma unroll
            for (int j = 0; j < 4; j++) {
                int s = (wave * 4 + j) * 64 + lane;
                int m = s >> 3, q = (s & 7) ^ (m & 7);
                ld16(&Bs[1 - p][(wave * 4 + j) * 512], w2T + (size_t)(n0 + m) * CA + k0 + q * 8);
            }
        }
        #pragma unroll
        for (int kk = 0; kk < 2; kk++) {
            const int cb0 = kk * 4 + lg;
            short8 af[2], bf[4];
            #pragma unroll
            for (int i2 = 0; i2 < 2; i2++) {
                int r = wm * 32 + i2 * 16 + lm;
                af[i2] = *(const short8*)&As[p][r * 64 + (cb0 ^ (r & 7)) * 8];
            }
            #pragma unroll
            for (int j = 0; j < 4; j++) {
                int r = wn * 64 + j * 16 + lm;
                bf[j] = *(const short8*)&Bs[p][r * 64 + (cb0 ^ (r & 7)) * 8];
            }
            #pragma unroll
            for (int i2 = 0; i2 < 2; i2++)
                #pragma unroll
                for (int j = 0; j < 4; j++)
                    acc[i2][j] = __builtin_amdgcn_mfma_f32_16x16x32_bf16(af[i2], bf[j], acc[i2][j], 0, 0, 0);
        }
    }

    #pragma unroll
    for (int i2 = 0; i2 < 2; i2++) {
        const int row0 = m0 + wm * 32 + i2 * 16 + lg * 4;
        #pragma unroll
        for (int j = 0; j < 4; j++) {
            const int col = n0 + wn * 64 + j * 16 + lm;
            const float bias = b2[col];
            #pragma unroll
            for (int r = 0; r < 4; r++) {
                const size_t idx = (size_t)(row0 + r) * DIM + col;
                out[idx] = acc[i2][j][r] + x[idx] + bias;
            }
        }
    }
}

// ---------------------------------------------------------------------------
extern "C" void kernel_launch(void* const* d_in, const int* in_sizes, int n_in,
                              void* d_out, int out_size, void* d_ws, size_t ws_size,
                              hipStream_t stream) {
    (void)in_sizes; (void)n_in; (void)out_size; (void)ws_size;
    const float* x      = (const float*)d_in[0];
    const float* w1     = (const float*)d_in[1];
    const float* b1     = (const float*)d_in[2];
    const float* conv_w = (const float*)d_in[3];
    const float* conv_b = (const float*)d_in[4];
    const float* w2     = (const float*)d_in[5];
    const float* b2     = (const float*)d_in[6];
    float* out = (float*)d_out;

    char* ws = (char*)d_ws;
    short* g   = (short*)ws;                           // 25216*192*2 = 9,682,944 B
    short* w1T = (short*)(ws + 9682944);               // 294,912 B
    short* w2T = (short*)(ws + 9682944 + 294912);      // 294,912 B

    prep_kernel<<<(CA * DIM + 255) / 256, 256, 0, stream>>>(w1, w2, w1T, w2T);
    gemm1_fused<<<784, 256, 0, stream>>>(x, w1T, b1, conv_w, conv_b, g);
    gemm2_kernel<<<dim3(394, 6), 256, 0, stream>>>(g, w2T, b2, x, out);
}